// Round 2
// baseline (10852.261 us; speedup 1.0000x reference)
//
#include <hip/hip_runtime.h>

// ---------------- problem constants ----------------
constexpr int cN  = 50000;
constexpr int cE  = 800000;
constexpr int cEU = 400000;
constexpr int cL2 = 131072;
constexpr int cEL = 1048576;
constexpr int cG  = 512;
constexpr int cH  = 128;
constexpr int cNH = 4;
constexpr int cNL = 2;

// encoder geometry — ESETS=8 (48 rows = 3 full M-tiles, zero pad waste).
// Weights (B-operands) hoisted into registers and reused across all 3 M-tiles:
// per-block L2 weight traffic drops 3.1 MB -> 1.05 MB (the R0/R1 bottleneck).
constexpr int ESETS = 8;          // sets per encoder block
constexpr int ERT   = ESETS * 6;  // 48 token rows = 3 M-tiles of 16
constexpr int MT    = 3;
constexpr int QS    = 388;        // fp32 QKV LDS stride (388 % 32 == 4 -> bank spread)
constexpr int AS    = 264;        // bf16 A LDS stride  (264*2/4 = 132 % 32 == 4)

// dynamic LDS layout (bytes)
constexpr int OFF_QKV = 0;                        // 48*388*4 = 74496
constexpr int OFF_AH  = 74496;                    // 48*264*2 = 25344
constexpr int OFF_AL  = OFF_AH + 25344;           // 99840
constexpr int OFF_ATT = OFF_AL + 25344;           // 125184 ; 8*4*36*4 = 4608
constexpr int OFF_IDX = OFF_ATT + 4608;           // 129792 ; 48 ints = 192
constexpr int SMEM_SZ = OFF_IDX + 192;            // 129,984 B

typedef __attribute__((ext_vector_type(8))) short short8v;
typedef __attribute__((ext_vector_type(4))) float f32x4;

#define DEVI __device__ __forceinline__

DEVI unsigned fmap(float x) {
  unsigned u = __float_as_uint(x);
  return (u & 0x80000000u) ? ~u : (u | 0x80000000u);
}
DEVI float funmap(unsigned m) {
  return __uint_as_float((m & 0x80000000u) ? (m & 0x7FFFFFFFu) : ~m);
}
DEVI float gelu_exact(float x) {
  return 0.5f * x * (1.0f + erff(x * 0.70710678118654752f));
}
DEVI unsigned short f2b_rn(float x) {            // fp32 -> bf16 round-nearest-even
  unsigned u = __float_as_uint(x);
  return (unsigned short)((u + 0x7FFFu + ((u >> 16) & 1u)) >> 16);
}
DEVI float b2f(unsigned short h) { return __uint_as_float(((unsigned)h) << 16); }
DEVI void sp1(unsigned short* hi, unsigned short* lo, int idx, float x) {
  unsigned short h = f2b_rn(x);
  hi[idx] = h;
  lo[idx] = f2b_rn(x - b2f(h));
}

// ---------------- tiny utility kernels ----------------
__global__ void fill_k(float* p, float v, int n) {
  int i = blockIdx.x * 256 + threadIdx.x;
  if (i < n) p[i] = v;
}

__global__ void deg_count_k(const int* __restrict__ ei, float* deg, int nE) {
  int e = blockIdx.x * 256 + threadIdx.x;
  if (e < nE) atomicAdd(&deg[ei[nE + e]], 1.0f);
}

__global__ void to_dinv_k(float* deg, int n) {
  int i = blockIdx.x * 256 + threadIdx.x;
  if (i < n) deg[i] = rsqrtf(deg[i]);
}

// split fp32 weights into bf16 hi/lo (error-compensated MFMA operands)
__global__ void split_w_k(const float* __restrict__ src, unsigned short* __restrict__ hi,
                          unsigned short* __restrict__ lo, int n) {
  int i = blockIdx.x * 256 + threadIdx.x;
  if (i < n) {
    float x = src[i];
    unsigned short h = f2b_rn(x);
    hi[i] = h;
    lo[i] = f2b_rn(x - b2f(h));
  }
}

// ---------------- generic C[M,128] = A[M,128] @ W[128,128]^T ----------------
__global__ __launch_bounds__(256) void gemm128_k(const float* __restrict__ A,
                                                 const float* __restrict__ W,
                                                 float* __restrict__ C, int M) {
  __shared__ float At[16][132];
  int c = threadIdx.x & 127, rr = threadIdx.x >> 7;
  int base = blockIdx.x * 128;
  for (int tile = 0; tile < 8; ++tile) {
    int r0 = base + tile * 16;
    if (r0 >= M) break;
    __syncthreads();
    for (int i = threadIdx.x; i < 16 * 32; i += 256) {
      int r = i >> 5, s4 = (i & 31) * 4;
      if (r0 + r < M) *(float4*)&At[r][s4] = *(const float4*)&A[(long)(r0 + r) * cH + s4];
    }
    __syncthreads();
    float acc[8];
    #pragma unroll
    for (int j = 0; j < 8; ++j) acc[j] = 0.f;
    const float* wr = W + (long)c * cH;
    for (int k = 0; k < cH; k += 4) {
      float4 w4 = *(const float4*)(wr + k);
      #pragma unroll
      for (int j = 0; j < 8; ++j) {
        float4 a4 = *(const float4*)&At[rr * 8 + j][k];
        acc[j] = fmaf(a4.x, w4.x, acc[j]);
        acc[j] = fmaf(a4.y, w4.y, acc[j]);
        acc[j] = fmaf(a4.z, w4.z, acc[j]);
        acc[j] = fmaf(a4.w, w4.w, acc[j]);
      }
    }
    #pragma unroll
    for (int j = 0; j < 8; ++j) {
      int r = r0 + rr * 8 + j;
      if (r < M) C[(long)r * cH + c] = acc[j];
    }
  }
}

// ---------------- GCN: out = b + dinv^2 * xw   (self-loop term) ----------------
__global__ void gcn_init_k(const float* __restrict__ xw, const float* __restrict__ dinv,
                           const float* __restrict__ bias, float* __restrict__ out, int n) {
  long idx = (long)blockIdx.x * 256 + threadIdx.x;
  if (idx >= (long)n * 32) return;
  int i = (int)(idx >> 5), q = (int)(idx & 31) * 4;
  float di = dinv[i], w = di * di;
  float4 v = *(const float4*)&xw[(long)i * cH + q];
  float4 b4 = *(const float4*)&bias[q];
  float4 o;
  o.x = b4.x + w * v.x; o.y = b4.y + w * v.y;
  o.z = b4.z + w * v.z; o.w = b4.w + w * v.w;
  *(float4*)&out[(long)i * cH + q] = o;
}

// ---------------- GCN edge aggregation (atomic scatter-add) ----------------
__global__ void gcn_agg_k(const float* __restrict__ xw, const float* __restrict__ dinv,
                          const int* __restrict__ ei, float* __restrict__ out, int nE) {
  long idx = (long)blockIdx.x * 256 + threadIdx.x;
  if (idx >= (long)nE * 32) return;
  int e = (int)(idx >> 5), q = (int)(idx & 31) * 4;
  int s = ei[e], d = ei[nE + e];
  float w = dinv[s] * dinv[d];
  float4 v = *(const float4*)&xw[(long)s * cH + q];
  float* op = &out[(long)d * cH + q];
  atomicAdd(op + 0, w * v.x);
  atomicAdd(op + 1, w * v.y);
  atomicAdd(op + 2, w * v.z);
  atomicAdd(op + 3, w * v.w);
}

// ---------------- fused 2-layer transformer encoder (MFMA split-bf16) ----------------
// 8 sets x 6 tokens = 48 rows = 3 M-tiles. B-operands (weights) are loaded ONCE
// into registers per phase and reused across all 3 M-tiles — the dominant cost
// in R0/R1 was this redundant L2 weight stream (~40 GB/s/CU invariant).
// hi/lo bf16 error compensation (3 MFMA per product, ~fp32 accuracy).
__global__ __launch_bounds__(512, 2) void encoder_k(
    const float* __restrict__ H0, const float* __restrict__ EA,
    const float* __restrict__ LEW, const float* __restrict__ LEB,
    const int* __restrict__ ue, const int* __restrict__ l2nm,
    const unsigned short* __restrict__ WinH, const unsigned short* __restrict__ WinL,
    const float* __restrict__ Bin,
    const unsigned short* __restrict__ WoutH, const unsigned short* __restrict__ WoutL,
    const float* __restrict__ Bout,
    const float* __restrict__ Ln1g, const float* __restrict__ Ln1b,
    const float* __restrict__ Ln2g, const float* __restrict__ Ln2b,
    const unsigned short* __restrict__ Wf1H, const unsigned short* __restrict__ Wf1L,
    const float* __restrict__ Bf1,
    const unsigned short* __restrict__ Wf2H, const unsigned short* __restrict__ Wf2L,
    const float* __restrict__ Bf2,
    float* __restrict__ H1) {
  extern __shared__ char smem[];
  float* QKV = (float*)(smem + OFF_QKV);               // [48][388] fp32
  unsigned short* Ahs = (unsigned short*)(smem + OFF_AH); // [48][264] bf16 hi
  unsigned short* Als = (unsigned short*)(smem + OFF_AL); // [48][264] bf16 lo
  float* att = (float*)(smem + OFF_ATT);               // [8*4*36]
  int* nidx = (int*)(smem + OFF_IDX);                  // 32 node ids
  int* eidx = nidx + 32;                               // 16 edge ids

  const int tid = threadIdx.x;
  const int lane = tid & 63, wv = tid >> 6;
  const int base = blockIdx.x * ESETS;

  if (tid < ESETS) {
    int e = l2nm[base + tid];
    int f = l2nm[cL2 + base + tid];
    eidx[tid * 2 + 0] = e;
    eidx[tid * 2 + 1] = f;
    nidx[tid * 4 + 0] = ue[e];
    nidx[tid * 4 + 1] = ue[cEU + e];
    nidx[tid * 4 + 2] = ue[f];
    nidx[tid * 4 + 3] = ue[cEU + f];
  }
  __syncthreads();
  // H0 rows (4 per set) -> A hi/lo
  for (int i = tid; i < 32 * 32; i += 512) {
    int q = i >> 5, s4 = (i & 31) * 4;
    int r = (q >> 2) * 6 + (q & 3);
    float4 v = *(const float4*)&H0[(long)nidx[q] * cH + s4];
    sp1(Ahs, Als, r * AS + s4 + 0, v.x);
    sp1(Ahs, Als, r * AS + s4 + 1, v.y);
    sp1(Ahs, Als, r * AS + s4 + 2, v.z);
    sp1(Ahs, Als, r * AS + s4 + 3, v.w);
  }
  // edge rows (2 per set): EA[e] @ LEW^T + LEB, on the fly
  for (int i = tid; i < ESETS * 2 * cH; i += 512) {
    int c = i & 127, q = i >> 7;
    const float* row = EA + (long)eidx[q] * 16;
    const float* wr = LEW + c * 16;
    float acc = LEB[c];
    #pragma unroll
    for (int d = 0; d < 16; ++d) acc = fmaf(row[d], wr[d], acc);
    int r = (q >> 1) * 6 + 4 + (q & 1);
    sp1(Ahs, Als, r * AS + c, acc);
  }
  __syncthreads();

  for (int l = 0; l < cNL; ++l) {
    // ---- qkv: [48,128] @ Win^T -> QKV fp32 [48][0..384) ----
    // A frags for all 3 M-tiles in regs (96 VGPR); B loaded once per ni (32 VGPR)
    {
      const unsigned short* WH = WinH + (long)l * 384 * 128;
      const unsigned short* WL = WinL + (long)l * 384 * 128;
      const float* BB = Bin + l * 384;
      short8v ah[3][4], al[3][4];
      #pragma unroll
      for (int m = 0; m < MT; ++m) {
        int ar = m * 16 + (lane & 15);
        int ac = (lane >> 4) << 3;
        #pragma unroll
        for (int ks = 0; ks < 4; ++ks) {
          ah[m][ks] = *(const short8v*)&Ahs[ar * AS + ac + ks * 32];
          al[m][ks] = *(const short8v*)&Als[ar * AS + ac + ks * 32];
        }
      }
      #pragma unroll
      for (int ni = 0; ni < 3; ++ni) {
        int col = (wv + 8 * ni) * 16 + (lane & 15);
        const unsigned short* wp = WH + (long)col * 128 + ((lane >> 4) << 3);
        const unsigned short* wq = WL + (long)col * 128 + ((lane >> 4) << 3);
        short8v bh[4], bl[4];
        #pragma unroll
        for (int ks = 0; ks < 4; ++ks) {
          bh[ks] = *(const short8v*)&wp[ks * 32];
          bl[ks] = *(const short8v*)&wq[ks * 32];
        }
        float bv = BB[col];
        #pragma unroll
        for (int m = 0; m < MT; ++m) {
          f32x4 acc = {0.f, 0.f, 0.f, 0.f};
          #pragma unroll
          for (int ks = 0; ks < 4; ++ks) {
            acc = __builtin_amdgcn_mfma_f32_16x16x32_bf16(al[m][ks], bh[ks], acc, 0, 0, 0);
            acc = __builtin_amdgcn_mfma_f32_16x16x32_bf16(ah[m][ks], bl[ks], acc, 0, 0, 0);
            acc = __builtin_amdgcn_mfma_f32_16x16x32_bf16(ah[m][ks], bh[ks], acc, 0, 0, 0);
          }
          int r0 = m * 16 + ((lane >> 4) << 2);
          #pragma unroll
          for (int j = 0; j < 4; ++j) QKV[(r0 + j) * QS + col] = acc[j] + bv;
        }
      }
    }
    __syncthreads();
    // ---- attention scores -> att ----
    for (int i = tid; i < ESETS * cNH * 36; i += 512) {
      int s = i / 144;
      int rem = i % 144;
      int h = rem / 36;
      int qt = (rem % 36) / 6;
      int kt = rem % 6;
      const float* qp = &QKV[(s * 6 + qt) * QS + h * 32];
      const float* kp = &QKV[(s * 6 + kt) * QS + 128 + h * 32];
      float d = 0.f;
      #pragma unroll
      for (int j4 = 0; j4 < 8; ++j4) {
        float4 a4 = *(const float4*)&qp[j4 * 4];
        float4 b4 = *(const float4*)&kp[j4 * 4];
        d = fmaf(a4.x, b4.x, d); d = fmaf(a4.y, b4.y, d);
        d = fmaf(a4.z, b4.z, d); d = fmaf(a4.w, b4.w, d);
      }
      att[i] = d * 0.17677669529663687f;   // 1/sqrt(32)
    }
    __syncthreads();
    // ---- softmax over k (rows of 6) ----
    if (tid < ESETS * cNH * 6) {
      float* row = &att[tid * 6];
      float m = row[0];
      #pragma unroll
      for (int kt = 1; kt < 6; ++kt) m = fmaxf(m, row[kt]);
      float ev[6]; float sum = 0.f;
      #pragma unroll
      for (int kt = 0; kt < 6; ++kt) { ev[kt] = expf(row[kt] - m); sum += ev[kt]; }
      float inv = 1.f / sum;
      #pragma unroll
      for (int kt = 0; kt < 6; ++kt) row[kt] = ev[kt] * inv;
    }
    __syncthreads();
    // ---- o = att @ v -> A hi/lo [.][128..256) ----
    for (int i = tid; i < ERT * cH; i += 512) {
      int r = i >> 7, c = i & 127;
      int s = r / 6, h = c >> 5;
      const float* arow = &att[((s * cNH + h) * 6 + (r % 6)) * 6];
      float d = 0.f;
      #pragma unroll
      for (int kt = 0; kt < 6; ++kt) d = fmaf(arow[kt], QKV[(s * 6 + kt) * QS + 256 + c], d);
      sp1(Ahs, Als, r * AS + 128 + c, d);
    }
    __syncthreads();
    // ---- out-proj: A[.][128..256) @ Wout^T -> QKV fp32 [.][0..128) ----
    // B loaded once (32 VGPR), reused across 3 M-tiles
    {
      const unsigned short* WH = WoutH + (long)l * 128 * 128;
      const unsigned short* WL = WoutL + (long)l * 128 * 128;
      int col = wv * 16 + (lane & 15);
      const unsigned short* wp = WH + (long)col * 128 + ((lane >> 4) << 3);
      const unsigned short* wq = WL + (long)col * 128 + ((lane >> 4) << 3);
      short8v bh[4], bl[4];
      #pragma unroll
      for (int ks = 0; ks < 4; ++ks) {
        bh[ks] = *(const short8v*)&wp[ks * 32];
        bl[ks] = *(const short8v*)&wq[ks * 32];
      }
      float bv = Bout[l * 128 + col];
      #pragma unroll
      for (int m = 0; m < MT; ++m) {
        int ar = m * 16 + (lane & 15);
        int ac = 128 + ((lane >> 4) << 3);
        f32x4 acc = {0.f, 0.f, 0.f, 0.f};
        #pragma unroll
        for (int ks = 0; ks < 4; ++ks) {
          short8v ah = *(const short8v*)&Ahs[ar * AS + ac + ks * 32];
          short8v al = *(const short8v*)&Als[ar * AS + ac + ks * 32];
          acc = __builtin_amdgcn_mfma_f32_16x16x32_bf16(al, bh[ks], acc, 0, 0, 0);
          acc = __builtin_amdgcn_mfma_f32_16x16x32_bf16(ah, bl[ks], acc, 0, 0, 0);
          acc = __builtin_amdgcn_mfma_f32_16x16x32_bf16(ah, bh[ks], acc, 0, 0, 0);
        }
        int r0 = m * 16 + ((lane >> 4) << 2);
        #pragma unroll
        for (int j = 0; j < 4; ++j) QKV[(r0 + j) * QS + col] = acc[j] + bv;
      }
    }
    __syncthreads();
    // ---- residual + LN1: y = xs + attn; xn -> A hi/lo [0..128) and QKV [128..256) ----
    {
      const float* gg = Ln1g + l * cH;
      const float* bb = Ln1b + l * cH;
      #pragma unroll
      for (int p = 0; p < MT; ++p) {
        int r = p * 16 + (tid >> 5);
        int c0 = (tid & 31) * 4;
        float y[4]; float s = 0.f, s2 = 0.f;
        #pragma unroll
        for (int j = 0; j < 4; ++j) {
          float xv = b2f(Ahs[r * AS + c0 + j]) + b2f(Als[r * AS + c0 + j]);
          float yv = xv + QKV[r * QS + c0 + j];
          y[j] = yv; s += yv; s2 += yv * yv;
        }
        #pragma unroll
        for (int m = 1; m < 32; m <<= 1) { s += __shfl_xor(s, m, 32); s2 += __shfl_xor(s2, m, 32); }
        float mean = s * (1.f / 128.f);
        float rstd = rsqrtf(s2 * (1.f / 128.f) - mean * mean + 1e-5f);
        #pragma unroll
        for (int j = 0; j < 4; ++j) {
          float xn = (y[j] - mean) * rstd * gg[c0 + j] + bb[c0 + j];
          QKV[r * QS + 128 + c0 + j] = xn;           // residual master for LN2
          sp1(Ahs, Als, r * AS + c0 + j, xn);        // A operand for ff1
        }
      }
    }
    __syncthreads();
    // ---- ff1: A[0..128) @ Wf1^T (N=256), hold in regs ----
    // A frags for all 3 M-tiles in regs; B once per ni
    f32x4 dreg[MT][2];
    {
      const unsigned short* WH = Wf1H + (long)l * 256 * 128;
      const unsigned short* WL = Wf1L + (long)l * 256 * 128;
      short8v ah[3][4], al[3][4];
      #pragma unroll
      for (int m = 0; m < MT; ++m) {
        int ar = m * 16 + (lane & 15);
        int ac = (lane >> 4) << 3;
        #pragma unroll
        for (int ks = 0; ks < 4; ++ks) {
          ah[m][ks] = *(const short8v*)&Ahs[ar * AS + ac + ks * 32];
          al[m][ks] = *(const short8v*)&Als[ar * AS + ac + ks * 32];
        }
      }
      #pragma unroll
      for (int ni = 0; ni < 2; ++ni) {
        int col = (wv + 8 * ni) * 16 + (lane & 15);
        const unsigned short* wp = WH + (long)col * 128 + ((lane >> 4) << 3);
        const unsigned short* wq = WL + (long)col * 128 + ((lane >> 4) << 3);
        short8v bh[4], bl[4];
        #pragma unroll
        for (int ks = 0; ks < 4; ++ks) {
          bh[ks] = *(const short8v*)&wp[ks * 32];
          bl[ks] = *(const short8v*)&wq[ks * 32];
        }
        #pragma unroll
        for (int m = 0; m < MT; ++m) {
          f32x4 acc = {0.f, 0.f, 0.f, 0.f};
          #pragma unroll
          for (int ks = 0; ks < 4; ++ks) {
            acc = __builtin_amdgcn_mfma_f32_16x16x32_bf16(al[m][ks], bh[ks], acc, 0, 0, 0);
            acc = __builtin_amdgcn_mfma_f32_16x16x32_bf16(ah[m][ks], bl[ks], acc, 0, 0, 0);
            acc = __builtin_amdgcn_mfma_f32_16x16x32_bf16(ah[m][ks], bh[ks], acc, 0, 0, 0);
          }
          dreg[m][ni] = acc;
        }
      }
    }
    __syncthreads();   // all reads of A done
    // ---- ff1 write: relu + split -> A hi/lo [0..256) ----
    #pragma unroll
    for (int m = 0; m < MT; ++m) {
      #pragma unroll
      for (int ni = 0; ni < 2; ++ni) {
        int col = (wv + 8 * ni) * 16 + (lane & 15);
        float bv = Bf1[l * 256 + col];
        int r0 = m * 16 + ((lane >> 4) << 2);
        #pragma unroll
        for (int j = 0; j < 4; ++j) {
          float h = fmaxf(dreg[m][ni][j] + bv, 0.f);
          sp1(Ahs, Als, (r0 + j) * AS + col, h);
        }
      }
    }
    __syncthreads();
    // ---- ff2: A[0..256) @ Wf2^T (K=256) -> QKV fp32 [0..128) ----
    // B (K=256: 8 ks) loaded once = 64 VGPR, reused across 3 M-tiles
    {
      const unsigned short* WH = Wf2H + (long)l * 128 * 256;
      const unsigned short* WL = Wf2L + (long)l * 128 * 256;
      int col = wv * 16 + (lane & 15);
      const unsigned short* wp = WH + (long)col * 256 + ((lane >> 4) << 3);
      const unsigned short* wq = WL + (long)col * 256 + ((lane >> 4) << 3);
      short8v bh[8], bl[8];
      #pragma unroll
      for (int ks = 0; ks < 8; ++ks) {
        bh[ks] = *(const short8v*)&wp[ks * 32];
        bl[ks] = *(const short8v*)&wq[ks * 32];
      }
      float bv = Bf2[l * 128 + col];
      #pragma unroll
      for (int m = 0; m < MT; ++m) {
        int ar = m * 16 + (lane & 15);
        int ac = (lane >> 4) << 3;
        f32x4 acc = {0.f, 0.f, 0.f, 0.f};
        #pragma unroll
        for (int ks = 0; ks < 8; ++ks) {
          short8v ah = *(const short8v*)&Ahs[ar * AS + ac + ks * 32];
          short8v al = *(const short8v*)&Als[ar * AS + ac + ks * 32];
          acc = __builtin_amdgcn_mfma_f32_16x16x32_bf16(al, bh[ks], acc, 0, 0, 0);
          acc = __builtin_amdgcn_mfma_f32_16x16x32_bf16(ah, bl[ks], acc, 0, 0, 0);
          acc = __builtin_amdgcn_mfma_f32_16x16x32_bf16(ah, bh[ks], acc, 0, 0, 0);
        }
        int r0 = m * 16 + ((lane >> 4) << 2);
        #pragma unroll
        for (int j = 0; j < 4; ++j) QKV[(r0 + j) * QS + col] = acc[j] + bv;
      }
    }
    __syncthreads();
    // ---- residual + LN2: y_resid(QKV[128..256)) + ff(QKV[0..128)) -> A hi/lo ----
    {
      const float* gg = Ln2g + l * cH;
      const float* bb = Ln2b + l * cH;
      #pragma unroll
      for (int p = 0; p < MT; ++p) {
        int r = p * 16 + (tid >> 5);
        int c0 = (tid & 31) * 4;
        float y[4]; float s = 0.f, s2 = 0.f;
        #pragma unroll
        for (int j = 0; j < 4; ++j) {
          float yv = QKV[r * QS + 128 + c0 + j] + QKV[r * QS + c0 + j];
          y[j] = yv; s += yv; s2 += yv * yv;
        }
        #pragma unroll
        for (int m = 1; m < 32; m <<= 1) { s += __shfl_xor(s, m, 32); s2 += __shfl_xor(s2, m, 32); }
        float mean = s * (1.f / 128.f);
        float rstd = rsqrtf(s2 * (1.f / 128.f) - mean * mean + 1e-5f);
        #pragma unroll
        for (int j = 0; j < 4; ++j) {
          float xn = (y[j] - mean) * rstd * gg[c0 + j] + bb[c0 + j];
          sp1(Ahs, Als, r * AS + c0 + j, xn);
        }
      }
    }
    __syncthreads();
  }

  // ---- H1 = mean over the 6 tokens ----
  for (int i = tid; i < ESETS * cH; i += 512) {
    int s = i >> 7, c = i & 127;
    float m = 0.f;
    #pragma unroll
    for (int t = 0; t < 6; ++t)
      m += b2f(Ahs[(s * 6 + t) * AS + c]) + b2f(Als[(s * 6 + t) * AS + c]);
    H1[(long)(base + s) * cH + c] = m * (1.f / 6.f);
  }
}

// ---------------- l2_batch = batch[ue0[l2nm0[i]]] ----------------
__global__ void l2b_k(const int* __restrict__ l2nm, const int* __restrict__ ue,
                      const int* __restrict__ batch, int* __restrict__ l2b) {
  int i = blockIdx.x * 256 + threadIdx.x;
  if (i < cL2) l2b[i] = batch[ue[l2nm[i]]];
}

// ---------------- pooling ----------------
__global__ void init_stats_k(float* sum, unsigned* mx, unsigned* mn, float* cnt) {
  int i = blockIdx.x * 256 + threadIdx.x;
  if (i < cG * cH) { sum[i] = 0.f; mx[i] = 0u; mn[i] = 0xFFFFFFFFu; }
  if (i < cG) cnt[i] = 0.f;
}

__global__ void pool_k(const float* __restrict__ X, const int* __restrict__ gidx,
                       float* sum, unsigned* mx, unsigned* mn, float* cnt,
                       int n, int do_relu) {
  long idx = (long)blockIdx.x * 256 + threadIdx.x;
  if (idx >= (long)n * 32) return;
  int i = (int)(idx >> 5), q = (int)(idx & 31) * 4;
  int g = gidx[i];
  float4 v = *(const float4*)&X[(long)i * cH + q];
  if (do_relu) {
    v.x = fmaxf(v.x, 0.f); v.y = fmaxf(v.y, 0.f);
    v.z = fmaxf(v.z, 0.f); v.w = fmaxf(v.w, 0.f);
  }
  long b = (long)g * cH + q;
  atomicAdd(&sum[b + 0], v.x); atomicAdd(&sum[b + 1], v.y);
  atomicAdd(&sum[b + 2], v.z); atomicAdd(&sum[b + 3], v.w);
  atomicMax(&mx[b + 0], fmap(v.x)); atomicMax(&mx[b + 1], fmap(v.y));
  atomicMax(&mx[b + 2], fmap(v.z)); atomicMax(&mx[b + 3], fmap(v.w));
  atomicMin(&mn[b + 0], fmap(v.x)); atomicMin(&mn[b + 1], fmap(v.y));
  atomicMin(&mn[b + 2], fmap(v.z)); atomicMin(&mn[b + 3], fmap(v.w));
  if (q == 0) atomicAdd(&cnt[g], 1.0f);
}

__global__ void pool_fin_k(const float* sum, const unsigned* mx, const unsigned* mn,
                           const float* cnt, float* Hp, int pool_idx) {
  int idx = blockIdx.x * 256 + threadIdx.x;
  if (idx >= cG * cH) return;
  int g = idx >> 7, c = idx & 127;
  float ct = cnt[g];
  float mean = sum[idx] / fmaxf(ct, 1.f);
  float mxv = (ct > 0.f) ? funmap(mx[idx]) : 0.f;
  float mnv = (ct > 0.f) ? funmap(mn[idx]) : 0.f;
  float* row = Hp + (long)g * (9 * cH) + pool_idx * 3 * cH;
  row[c] = mnv;
  row[cH + c] = mxv;
  row[2 * cH + c] = mean;
}

// ---------------- final MLP per graph ----------------
__global__ __launch_bounds__(128) void mlp_k(
    const float* __restrict__ Hp,
    const float* __restrict__ f0w, const float* __restrict__ f0b,
    const float* __restrict__ f0g, const float* __restrict__ f0bb,
    const float* __restrict__ f1w, const float* __restrict__ f1b,
    const float* __restrict__ f1g, const float* __restrict__ f1bb,
    const float* __restrict__ fow, const float* __restrict__ fob,
    float* __restrict__ out) {
  __shared__ float hin[1152];
  __shared__ float red[8];
  int g = blockIdx.x, tid = threadIdx.x;
  const float* hp = Hp + (long)g * 1152;
  for (int i = tid; i < 1152; i += 128) hin[i] = hp[i];
  __syncthreads();
  float acc = f0b[tid];
  {
    const float* wr = f0w + (long)tid * 1152;
    for (int k = 0; k < 1152; k += 4) {
      float4 w4 = *(const float4*)(wr + k);
      float4 h4 = *(const float4*)&hin[k];
      acc = fmaf(h4.x, w4.x, acc);
      acc = fmaf(h4.y, w4.y, acc);
      acc = fmaf(h4.z, w4.z, acc);
      acc = fmaf(h4.w, w4.w, acc);
    }
  }
  float s = acc, s2 = acc * acc;
  #pragma unroll
  for (int m = 1; m < 64; m <<= 1) { s += __shfl_xor(s, m); s2 += __shfl_xor(s2, m); }
  if ((tid & 63) == 0) { red[tid >> 6] = s; red[4 + (tid >> 6)] = s2; }
  __syncthreads();
  s = red[0] + red[1]; s2 = red[4] + red[5];
  {
    float mean = s * (1.f / 128.f);
    float rstd = rsqrtf(s2 * (1.f / 128.f) - mean * mean + 1e-5f);
    float xn = (acc - mean) * rstd * f0g[tid] + f0bb[tid];
    float h0 = gelu_exact(xn);
    __syncthreads();
    hin[tid] = h0;
  }
  __syncthreads();
  acc = f1b[tid];
  {
    const float* wr = f1w + (long)tid * 128;
    for (int k = 0; k < 128; k += 4) {
      float4 w4 = *(const float4*)(wr + k);
      float4 h4 = *(const float4*)&hin[k];
      acc = fmaf(h4.x, w4.x, acc);
      acc = fmaf(h4.y, w4.y, acc);
      acc = fmaf(h4.z, w4.z, acc);
      acc = fmaf(h4.w, w4.w, acc);
    }
  }
  s = acc; s2 = acc * acc;
  #pragma unroll
  for (int m = 1; m < 64; m <<= 1) { s += __shfl_xor(s, m); s2 += __shfl_xor(s2, m); }
  __syncthreads();
  if ((tid & 63) == 0) { red[tid >> 6] = s; red[4 + (tid >> 6)] = s2; }
  __syncthreads();
  s = red[0] + red[1]; s2 = red[4] + red[5];
  float h1;
  {
    float mean = s * (1.f / 128.f);
    float rstd = rsqrtf(s2 * (1.f / 128.f) - mean * mean + 1e-5f);
    float xn = (acc - mean) * rstd * f1g[tid] + f1bb[tid];
    h1 = gelu_exact(xn);
  }
  float p = h1 * fow[tid];
  #pragma unroll
  for (int m = 1; m < 64; m <<= 1) p += __shfl_xor(p, m);
  __syncthreads();
  if ((tid & 63) == 0) red[tid >> 6] = p;
  __syncthreads();
  if (tid == 0) out[g] = red[0] + red[1] + fob[0];
}

// ---------------- launcher ----------------
extern "C" void kernel_launch(void* const* d_in, const int* in_sizes, int n_in,
                              void* d_out, int out_size, void* d_ws, size_t ws_size,
                              hipStream_t stream) {
  const float* x     = (const float*)d_in[0];
  const float* ea    = (const float*)d_in[1];
  const int*   ei    = (const int*)d_in[2];
  const int*   ue    = (const int*)d_in[3];
  const int*   batch = (const int*)d_in[4];
  const int*   l2nm  = (const int*)d_in[5];
  const int*   l2ei  = (const int*)d_in[6];
  const float* lew   = (const float*)d_in[8];
  const float* leb   = (const float*)d_in[9];
  const float* g1w   = (const float*)d_in[10];
  const float* g1b   = (const float*)d_in[11];
  const float* g2w   = (const float*)d_in[12];
  const float* g2b   = (const float*)d_in[13];
  const float* tinw  = (const float*)d_in[14];
  const float* tinb  = (const float*)d_in[15];
  const float* toutw = (const float*)d_in[16];
  const float* toutb = (const float*)d_in[17];
  const float* tl1g  = (const float*)d_in[18];
  const float* tl1b  = (const float*)d_in[19];
  const float* tl2g  = (const float*)d_in[20];
  const float* tl2b  = (const float*)d_in[21];
  const float* tf1w  = (const float*)d_in[22];
  const float* tf1b  = (const float*)d_in[23];
  const float* tf2w  = (const float*)d_in[24];
  const float* tf2b  = (const float*)d_in[25];
  const float* f0w   = (const float*)d_in[26];
  const float* f0b   = (const float*)d_in[27];
  const float* f0g   = (const float*)d_in[28];
  const float* f0bb  = (const float*)d_in[29];
  const float* f1w   = (const float*)d_in[30];
  const float* f1b   = (const float*)d_in[31];
  const float* f1g   = (const float*)d_in[32];
  const float* f1bb  = (const float*)d_in[33];
  const float* fow   = (const float*)d_in[34];
  const float* fob   = (const float*)d_in[35];
  float* out = (float*)d_out;

  char* ws = (char*)d_ws;
  size_t off = 0;
  float* H1  = (float*)(ws + off);  off += (size_t)cL2 * cH * 4;
  float* RA  = (float*)(ws + off);  off += (size_t)cL2 * cH * 4;   // H0 then H2
  float* XW  = (float*)(ws + off);  off += (size_t)cL2 * cH * 4;
  float* DEG = (float*)(ws + off);  off += (size_t)cL2 * 4;
  int*   L2B = (int*)(ws + off);    off += (size_t)cL2 * 4;
  char*  ST  = ws + off;            off += 3 * ((size_t)cG * cH * 4 * 3 + cG * 4);
  float* Hp  = (float*)(ws + off);  off += (size_t)cG * 9 * cH * 4;
  // split-bf16 weight buffers
  unsigned short* WinH  = (unsigned short*)(ws + off); off += (size_t)cNL * 384 * 128 * 2;
  unsigned short* WinL  = (unsigned short*)(ws + off); off += (size_t)cNL * 384 * 128 * 2;
  unsigned short* WoutH = (unsigned short*)(ws + off); off += (size_t)cNL * 128 * 128 * 2;
  unsigned short* WoutL = (unsigned short*)(ws + off); off += (size_t)cNL * 128 * 128 * 2;
  unsigned short* Wf1H  = (unsigned short*)(ws + off); off += (size_t)cNL * 256 * 128 * 2;
  unsigned short* Wf1L  = (unsigned short*)(ws + off); off += (size_t)cNL * 256 * 128 * 2;
  unsigned short* Wf2H  = (unsigned short*)(ws + off); off += (size_t)cNL * 128 * 256 * 2;
  unsigned short* Wf2L  = (unsigned short*)(ws + off); off += (size_t)cNL * 128 * 256 * 2;
  float* H0 = RA;
  float* H2 = RA;

  auto stat = [&](int p) {
    size_t stride = (size_t)cG * cH * 4 * 3 + cG * 4;
    char* b = ST + p * stride;
    struct S { float* sum; unsigned* mx; unsigned* mn; float* cnt; } s;
    s.sum = (float*)b;
    s.mx  = (unsigned*)(b + (size_t)cG * cH * 4);
    s.mn  = (unsigned*)(b + (size_t)cG * cH * 8);
    s.cnt = (float*)(b + (size_t)cG * cH * 12);
    return s;
  };
  auto s0 = stat(0), s1 = stat(1), s2 = stat(2);

  // 0) split transformer weights into bf16 hi/lo
  split_w_k<<<(cNL * 384 * 128 + 255) / 256, 256, 0, stream>>>(tinw, WinH, WinL, cNL * 384 * 128);
  split_w_k<<<(cNL * 128 * 128 + 255) / 256, 256, 0, stream>>>(toutw, WoutH, WoutL, cNL * 128 * 128);
  split_w_k<<<(cNL * 256 * 128 + 255) / 256, 256, 0, stream>>>(tf1w, Wf1H, Wf1L, cNL * 256 * 128);
  split_w_k<<<(cNL * 128 * 256 + 255) / 256, 256, 0, stream>>>(tf2w, Wf2H, Wf2L, cNL * 128 * 256);

  // 1) GCN1 -> H0
  gemm128_k<<<(cN + 127) / 128, 256, 0, stream>>>(x, g1w, XW, cN);
  fill_k<<<(cN + 255) / 256, 256, 0, stream>>>(DEG, 1.0f, cN);
  deg_count_k<<<(cE + 255) / 256, 256, 0, stream>>>(ei, DEG, cE);
  to_dinv_k<<<(cN + 255) / 256, 256, 0, stream>>>(DEG, cN);
  gcn_init_k<<<(cN * 32 + 255) / 256, 256, 0, stream>>>(XW, DEG, g1b, H0, cN);
  gcn_agg_k<<<(int)(((long)cE * 32 + 255) / 256), 256, 0, stream>>>(XW, DEG, ei, H0, cE);

  // 2) fused MFMA transformer encoder -> H1
  hipFuncSetAttribute(reinterpret_cast<const void*>(encoder_k),
                      hipFuncAttributeMaxDynamicSharedMemorySize, 131072);
  encoder_k<<<cL2 / ESETS, 512, SMEM_SZ, stream>>>(H0, ea, lew, leb, ue, l2nm,
      WinH, WinL, tinb, WoutH, WoutL, toutb, tl1g, tl1b, tl2g, tl2b,
      Wf1H, Wf1L, tf1b, Wf2H, Wf2L, tf2b, H1);

  // 3) l2_batch
  l2b_k<<<(cL2 + 255) / 256, 256, 0, stream>>>(l2nm, ue, batch, L2B);
  // 4) pool H0 now (frees RA for H2)
  init_stats_k<<<(cG * cH + 255) / 256, 256, 0, stream>>>(s0.sum, s0.mx, s0.mn, s0.cnt);
  pool_k<<<(int)(((long)cN * 32 + 255) / 256), 256, 0, stream>>>(H0, batch, s0.sum, s0.mx, s0.mn, s0.cnt, cN, 0);
  pool_fin_k<<<(cG * cH + 255) / 256, 256, 0, stream>>>(s0.sum, s0.mx, s0.mn, s0.cnt, Hp, 0);
  // 5) GCN2 -> H2
  gemm128_k<<<(cL2 + 127) / 128, 256, 0, stream>>>(H1, g2w, XW, cL2);
  fill_k<<<(cL2 + 255) / 256, 256, 0, stream>>>(DEG, 1.0f, cL2);
  deg_count_k<<<(cEL + 255) / 256, 256, 0, stream>>>(l2ei, DEG, cEL);
  to_dinv_k<<<(cL2 + 255) / 256, 256, 0, stream>>>(DEG, cL2);
  gcn_init_k<<<(cL2 * 32 + 255) / 256, 256, 0, stream>>>(XW, DEG, g2b, H2, cL2);
  gcn_agg_k<<<(int)(((long)cEL * 32 + 255) / 256), 256, 0, stream>>>(XW, DEG, l2ei, H2, cEL);
  // 6) pool H1 and H2
  init_stats_k<<<(cG * cH + 255) / 256, 256, 0, stream>>>(s1.sum, s1.mx, s1.mn, s1.cnt);
  init_stats_k<<<(cG * cH + 255) / 256, 256, 0, stream>>>(s2.sum, s2.mx, s2.mn, s2.cnt);
  pool_k<<<(int)(((long)cL2 * 32 + 255) / 256), 256, 0, stream>>>(H1, L2B, s1.sum, s1.mx, s1.mn, s1.cnt, cL2, 0);
  pool_k<<<(int)(((long)cL2 * 32 + 255) / 256), 256, 0, stream>>>(H2, L2B, s2.sum, s2.mx, s2.mn, s2.cnt, cL2, 1);
  pool_fin_k<<<(cG * cH + 255) / 256, 256, 0, stream>>>(s1.sum, s1.mx, s1.mn, s1.cnt, Hp, 1);
  pool_fin_k<<<(cG * cH + 255) / 256, 256, 0, stream>>>(s2.sum, s2.mx, s2.mn, s2.cnt, Hp, 2);
  // 7) final MLP -> out[512]
  mlp_k<<<cG, 128, 0, stream>>>(Hp, f0w, f0b, f0g, f0bb, f1w, f1b, f1g, f1bb, fow, fob, out);
}

// Round 3
// 8824.837 us; speedup vs baseline: 1.2297x; 1.2297x over previous
//
#include <hip/hip_runtime.h>

// ---------------- problem constants ----------------
constexpr int cN  = 50000;
constexpr int cE  = 800000;
constexpr int cEU = 400000;
constexpr int cL2 = 131072;
constexpr int cEL = 1048576;
constexpr int cG  = 512;
constexpr int cH  = 128;
constexpr int cNH = 4;
constexpr int cNL = 2;

// encoder geometry — ESETS=8 (48 rows = 3 full M-tiles).
constexpr int ESETS = 8;          // sets per encoder block
constexpr int ERT   = ESETS * 6;  // 48 token rows = 3 M-tiles of 16
constexpr int MT    = 3;
constexpr int QS    = 388;        // fp32 QKV LDS stride (388 % 32 == 4 -> bank spread)
constexpr int AS    = 264;        // bf16 A LDS stride  (264*2/4 = 132 % 32 == 4)

// dynamic LDS layout (bytes)
constexpr int OFF_QKV = 0;                        // 48*388*4 = 74496
constexpr int OFF_AH  = 74496;                    // 48*264*2 = 25344
constexpr int OFF_AL  = OFF_AH + 25344;           // 99840
constexpr int OFF_ATT = OFF_AL + 25344;           // 125184 ; 8*144*4 = 4608
constexpr int OFF_IDX = OFF_ATT + 4608;           // 129792 ; 48 ints = 192
constexpr int SMEM_SZ = OFF_IDX + 192;            // 129,984 B

typedef __attribute__((ext_vector_type(8))) short short8v;
typedef __attribute__((ext_vector_type(4))) float f32x4;

#define DEVI __device__ __forceinline__

DEVI unsigned fmap(float x) {
  unsigned u = __float_as_uint(x);
  return (u & 0x80000000u) ? ~u : (u | 0x80000000u);
}
DEVI float funmap(unsigned m) {
  return __uint_as_float((m & 0x80000000u) ? (m & 0x7FFFFFFFu) : ~m);
}
DEVI float gelu_exact(float x) {
  return 0.5f * x * (1.0f + erff(x * 0.70710678118654752f));
}
DEVI unsigned short f2b_rn(float x) {            // fp32 -> bf16 round-nearest-even
  unsigned u = __float_as_uint(x);
  return (unsigned short)((u + 0x7FFFu + ((u >> 16) & 1u)) >> 16);
}
DEVI float b2f(unsigned short h) { return __uint_as_float(((unsigned)h) << 16); }
DEVI void sp1(unsigned short* hi, unsigned short* lo, int idx, float x) {
  unsigned short h = f2b_rn(x);
  hi[idx] = h;
  lo[idx] = f2b_rn(x - b2f(h));
}

// ---------------- tiny utility kernels ----------------
__global__ void fill_k(float* p, float v, int n) {
  int i = blockIdx.x * 256 + threadIdx.x;
  if (i < n) p[i] = v;
}

__global__ void deg_count_k(const int* __restrict__ ei, float* deg, int nE) {
  int e = blockIdx.x * 256 + threadIdx.x;
  if (e < nE) atomicAdd(&deg[ei[nE + e]], 1.0f);
}

__global__ void to_dinv_k(float* deg, int n) {
  int i = blockIdx.x * 256 + threadIdx.x;
  if (i < n) deg[i] = rsqrtf(deg[i]);
}

// split fp32 weights into bf16 hi/lo (error-compensated MFMA operands)
__global__ void split_w_k(const float* __restrict__ src, unsigned short* __restrict__ hi,
                          unsigned short* __restrict__ lo, int n) {
  int i = blockIdx.x * 256 + threadIdx.x;
  if (i < n) {
    float x = src[i];
    unsigned short h = f2b_rn(x);
    hi[i] = h;
    lo[i] = f2b_rn(x - b2f(h));
  }
}

// ---------------- generic C[M,128] = A[M,128] @ W[128,128]^T ----------------
__global__ __launch_bounds__(256) void gemm128_k(const float* __restrict__ A,
                                                 const float* __restrict__ W,
                                                 float* __restrict__ C, int M) {
  __shared__ float At[16][132];
  int c = threadIdx.x & 127, rr = threadIdx.x >> 7;
  int base = blockIdx.x * 128;
  for (int tile = 0; tile < 8; ++tile) {
    int r0 = base + tile * 16;
    if (r0 >= M) break;
    __syncthreads();
    for (int i = threadIdx.x; i < 16 * 32; i += 256) {
      int r = i >> 5, s4 = (i & 31) * 4;
      if (r0 + r < M) *(float4*)&At[r][s4] = *(const float4*)&A[(long)(r0 + r) * cH + s4];
    }
    __syncthreads();
    float acc[8];
    #pragma unroll
    for (int j = 0; j < 8; ++j) acc[j] = 0.f;
    const float* wr = W + (long)c * cH;
    for (int k = 0; k < cH; k += 4) {
      float4 w4 = *(const float4*)(wr + k);
      #pragma unroll
      for (int j = 0; j < 8; ++j) {
        float4 a4 = *(const float4*)&At[rr * 8 + j][k];
        acc[j] = fmaf(a4.x, w4.x, acc[j]);
        acc[j] = fmaf(a4.y, w4.y, acc[j]);
        acc[j] = fmaf(a4.z, w4.z, acc[j]);
        acc[j] = fmaf(a4.w, w4.w, acc[j]);
      }
    }
    #pragma unroll
    for (int j = 0; j < 8; ++j) {
      int r = r0 + rr * 8 + j;
      if (r < M) C[(long)r * cH + c] = acc[j];
    }
  }
}

// ---------------- GCN: out = b + dinv^2 * xw   (self-loop term) ----------------
__global__ void gcn_init_k(const float* __restrict__ xw, const float* __restrict__ dinv,
                           const float* __restrict__ bias, float* __restrict__ out, int n) {
  long idx = (long)blockIdx.x * 256 + threadIdx.x;
  if (idx >= (long)n * 32) return;
  int i = (int)(idx >> 5), q = (int)(idx & 31) * 4;
  float di = dinv[i], w = di * di;
  float4 v = *(const float4*)&xw[(long)i * cH + q];
  float4 b4 = *(const float4*)&bias[q];
  float4 o;
  o.x = b4.x + w * v.x; o.y = b4.y + w * v.y;
  o.z = b4.z + w * v.z; o.w = b4.w + w * v.w;
  *(float4*)&out[(long)i * cH + q] = o;
}

// ---------------- GCN edge aggregation (atomic scatter-add) ----------------
__global__ void gcn_agg_k(const float* __restrict__ xw, const float* __restrict__ dinv,
                          const int* __restrict__ ei, float* __restrict__ out, int nE) {
  long idx = (long)blockIdx.x * 256 + threadIdx.x;
  if (idx >= (long)nE * 32) return;
  int e = (int)(idx >> 5), q = (int)(idx & 31) * 4;
  int s = ei[e], d = ei[nE + e];
  float w = dinv[s] * dinv[d];
  float4 v = *(const float4*)&xw[(long)s * cH + q];
  float* op = &out[(long)d * cH + q];
  atomicAdd(op + 0, w * v.x);
  atomicAdd(op + 1, w * v.y);
  atomicAdd(op + 2, w * v.z);
  atomicAdd(op + 3, w * v.w);
}

// ---------------- fused 2-layer transformer encoder (MFMA split-bf16) ----------------
// 8 sets x 6 tokens = 48 rows = 3 M-tiles.
// MFMA phases: ks-outer / m-inner with SPLIT hi/lo accumulators -> 6 independent
// accumulation chains (R0 had 1 chain of 12 dependent MFMAs = latency-bound).
// A-frags reloaded from LDS per (ks,m): low register pressure, NO spills.
// B loaded once per (ni,ks) -> 3x less weight L2 traffic than R0.
// Attention (scores+softmax+AV) fused into ONE barrier-free per-wave phase.
__global__ __launch_bounds__(512, 1) void encoder_k(
    const float* __restrict__ H0, const float* __restrict__ EA,
    const float* __restrict__ LEW, const float* __restrict__ LEB,
    const int* __restrict__ ue, const int* __restrict__ l2nm,
    const unsigned short* __restrict__ WinH, const unsigned short* __restrict__ WinL,
    const float* __restrict__ Bin,
    const unsigned short* __restrict__ WoutH, const unsigned short* __restrict__ WoutL,
    const float* __restrict__ Bout,
    const float* __restrict__ Ln1g, const float* __restrict__ Ln1b,
    const float* __restrict__ Ln2g, const float* __restrict__ Ln2b,
    const unsigned short* __restrict__ Wf1H, const unsigned short* __restrict__ Wf1L,
    const float* __restrict__ Bf1,
    const unsigned short* __restrict__ Wf2H, const unsigned short* __restrict__ Wf2L,
    const float* __restrict__ Bf2,
    float* __restrict__ H1) {
  extern __shared__ char smem[];
  float* QKV = (float*)(smem + OFF_QKV);               // [48][388] fp32
  unsigned short* Ahs = (unsigned short*)(smem + OFF_AH); // [48][264] bf16 hi
  unsigned short* Als = (unsigned short*)(smem + OFF_AL); // [48][264] bf16 lo
  float* att = (float*)(smem + OFF_ATT);               // [8][144]
  int* nidx = (int*)(smem + OFF_IDX);                  // 32 node ids
  int* eidx = nidx + 32;                               // 16 edge ids

  const int tid = threadIdx.x;
  const int lane = tid & 63, wv = tid >> 6;
  const int lr = lane & 15, lq = lane >> 4;
  const int base = blockIdx.x * ESETS;

  if (tid < ESETS) {
    int e = l2nm[base + tid];
    int f = l2nm[cL2 + base + tid];
    eidx[tid * 2 + 0] = e;
    eidx[tid * 2 + 1] = f;
    nidx[tid * 4 + 0] = ue[e];
    nidx[tid * 4 + 1] = ue[cEU + e];
    nidx[tid * 4 + 2] = ue[f];
    nidx[tid * 4 + 3] = ue[cEU + f];
  }
  __syncthreads();
  // H0 rows (4 per set) -> A hi/lo
  for (int i = tid; i < 32 * 32; i += 512) {
    int q = i >> 5, s4 = (i & 31) * 4;
    int r = (q >> 2) * 6 + (q & 3);
    float4 v = *(const float4*)&H0[(long)nidx[q] * cH + s4];
    sp1(Ahs, Als, r * AS + s4 + 0, v.x);
    sp1(Ahs, Als, r * AS + s4 + 1, v.y);
    sp1(Ahs, Als, r * AS + s4 + 2, v.z);
    sp1(Ahs, Als, r * AS + s4 + 3, v.w);
  }
  // edge rows (2 per set): EA[e] @ LEW^T + LEB, on the fly
  for (int i = tid; i < ESETS * 2 * cH; i += 512) {
    int c = i & 127, q = i >> 7;
    const float* row = EA + (long)eidx[q] * 16;
    const float* wr = LEW + c * 16;
    float acc = LEB[c];
    #pragma unroll
    for (int d = 0; d < 16; ++d) acc = fmaf(row[d], wr[d], acc);
    int r = (q >> 1) * 6 + 4 + (q & 1);
    sp1(Ahs, Als, r * AS + c, acc);
  }
  __syncthreads();

  for (int l = 0; l < cNL; ++l) {
    // ---- qkv: [48,128] @ Win^T -> QKV fp32 [48][0..384) ----
    {
      const unsigned short* WH = WinH + (long)l * 384 * 128;
      const unsigned short* WL = WinL + (long)l * 384 * 128;
      const float* BB = Bin + l * 384;
      #pragma unroll
      for (int ni = 0; ni < 3; ++ni) {
        int col = (wv + 8 * ni) * 16 + lr;
        const unsigned short* wp = WH + (long)col * 128 + (lq << 3);
        const unsigned short* wq = WL + (long)col * 128 + (lq << 3);
        f32x4 accH[MT], accL[MT];
        #pragma unroll
        for (int m = 0; m < MT; ++m) {
          accH[m] = (f32x4){0.f, 0.f, 0.f, 0.f};
          accL[m] = (f32x4){0.f, 0.f, 0.f, 0.f};
        }
        #pragma unroll
        for (int ks = 0; ks < 4; ++ks) {
          short8v bh = *(const short8v*)&wp[ks * 32];
          short8v bl = *(const short8v*)&wq[ks * 32];
          #pragma unroll
          for (int m = 0; m < MT; ++m) {
            int ao = (m * 16 + lr) * AS + (lq << 3) + ks * 32;
            short8v ah = *(const short8v*)&Ahs[ao];
            short8v al = *(const short8v*)&Als[ao];
            accL[m] = __builtin_amdgcn_mfma_f32_16x16x32_bf16(al, bh, accL[m], 0, 0, 0);
            accL[m] = __builtin_amdgcn_mfma_f32_16x16x32_bf16(ah, bl, accL[m], 0, 0, 0);
            accH[m] = __builtin_amdgcn_mfma_f32_16x16x32_bf16(ah, bh, accH[m], 0, 0, 0);
          }
        }
        float bv = BB[col];
        #pragma unroll
        for (int m = 0; m < MT; ++m) {
          int r0 = m * 16 + (lq << 2);
          #pragma unroll
          for (int j = 0; j < 4; ++j)
            QKV[(r0 + j) * QS + col] = accH[m][j] + accL[m][j] + bv;
        }
      }
    }
    __syncthreads();
    // ---- fused attention: wave s owns set s; no block barriers inside ----
    {
      const int s = wv;
      float* attS = att + s * 144;
      if (lane < 24) {
        int h = lane / 6, qt = lane % 6;
        const float* qp = &QKV[(s * 6 + qt) * QS + h * 32];
        float4 qv[8];
        #pragma unroll
        for (int j4 = 0; j4 < 8; ++j4) qv[j4] = *(const float4*)&qp[j4 * 4];
        float sc[6];
        #pragma unroll
        for (int kt = 0; kt < 6; ++kt) {
          const float* kp = &QKV[(s * 6 + kt) * QS + 128 + h * 32];
          float d = 0.f;
          #pragma unroll
          for (int j4 = 0; j4 < 8; ++j4) {
            float4 b4 = *(const float4*)&kp[j4 * 4];
            d = fmaf(qv[j4].x, b4.x, d); d = fmaf(qv[j4].y, b4.y, d);
            d = fmaf(qv[j4].z, b4.z, d); d = fmaf(qv[j4].w, b4.w, d);
          }
          sc[kt] = d * 0.17677669529663687f;   // 1/sqrt(32)
        }
        float mx = sc[0];
        #pragma unroll
        for (int kt = 1; kt < 6; ++kt) mx = fmaxf(mx, sc[kt]);
        float ev[6]; float sum = 0.f;
        #pragma unroll
        for (int kt = 0; kt < 6; ++kt) { ev[kt] = expf(sc[kt] - mx); sum += ev[kt]; }
        float inv = 1.f / sum;
        #pragma unroll
        for (int kt = 0; kt < 6; ++kt) attS[(h * 6 + qt) * 6 + kt] = ev[kt] * inv;
      }
      // wave-local fence: prob writes -> AV reads (same wave, no block barrier)
      asm volatile("s_waitcnt lgkmcnt(0)" ::: "memory");
      __builtin_amdgcn_sched_barrier(0);
      #pragma unroll
      for (int it = 0; it < 12; ++it) {        // 6*128 outputs / 64 lanes
        int i = it * 64 + lane;
        int r = i >> 7, c = i & 127, h = c >> 5;
        const float* arow = &attS[(h * 6 + r) * 6];
        float d = 0.f;
        #pragma unroll
        for (int kt = 0; kt < 6; ++kt)
          d = fmaf(arow[kt], QKV[(s * 6 + kt) * QS + 256 + c], d);
        sp1(Ahs, Als, (s * 6 + r) * AS + 128 + c, d);
      }
    }
    __syncthreads();
    // ---- out-proj: A[.][128..256) @ Wout^T -> QKV fp32 [.][0..128) ----
    {
      const unsigned short* WH = WoutH + (long)l * 128 * 128;
      const unsigned short* WL = WoutL + (long)l * 128 * 128;
      int col = wv * 16 + lr;
      const unsigned short* wp = WH + (long)col * 128 + (lq << 3);
      const unsigned short* wq = WL + (long)col * 128 + (lq << 3);
      f32x4 accH[MT], accL[MT];
      #pragma unroll
      for (int m = 0; m < MT; ++m) {
        accH[m] = (f32x4){0.f, 0.f, 0.f, 0.f};
        accL[m] = (f32x4){0.f, 0.f, 0.f, 0.f};
      }
      #pragma unroll
      for (int ks = 0; ks < 4; ++ks) {
        short8v bh = *(const short8v*)&wp[ks * 32];
        short8v bl = *(const short8v*)&wq[ks * 32];
        #pragma unroll
        for (int m = 0; m < MT; ++m) {
          int ao = (m * 16 + lr) * AS + 128 + (lq << 3) + ks * 32;
          short8v ah = *(const short8v*)&Ahs[ao];
          short8v al = *(const short8v*)&Als[ao];
          accL[m] = __builtin_amdgcn_mfma_f32_16x16x32_bf16(al, bh, accL[m], 0, 0, 0);
          accL[m] = __builtin_amdgcn_mfma_f32_16x16x32_bf16(ah, bl, accL[m], 0, 0, 0);
          accH[m] = __builtin_amdgcn_mfma_f32_16x16x32_bf16(ah, bh, accH[m], 0, 0, 0);
        }
      }
      float bv = Bout[l * 128 + col];
      #pragma unroll
      for (int m = 0; m < MT; ++m) {
        int r0 = m * 16 + (lq << 2);
        #pragma unroll
        for (int j = 0; j < 4; ++j)
          QKV[(r0 + j) * QS + col] = accH[m][j] + accL[m][j] + bv;
      }
    }
    __syncthreads();
    // ---- residual + LN1: y = xs + attn; xn -> A hi/lo [0..128) and QKV [128..256) ----
    {
      const float* gg = Ln1g + l * cH;
      const float* bb = Ln1b + l * cH;
      #pragma unroll
      for (int p = 0; p < MT; ++p) {
        int r = p * 16 + (tid >> 5);
        int c0 = (tid & 31) * 4;
        float y[4]; float s = 0.f, s2 = 0.f;
        #pragma unroll
        for (int j = 0; j < 4; ++j) {
          float xv = b2f(Ahs[r * AS + c0 + j]) + b2f(Als[r * AS + c0 + j]);
          float yv = xv + QKV[r * QS + c0 + j];
          y[j] = yv; s += yv; s2 += yv * yv;
        }
        #pragma unroll
        for (int m = 1; m < 32; m <<= 1) { s += __shfl_xor(s, m, 32); s2 += __shfl_xor(s2, m, 32); }
        float mean = s * (1.f / 128.f);
        float rstd = rsqrtf(s2 * (1.f / 128.f) - mean * mean + 1e-5f);
        #pragma unroll
        for (int j = 0; j < 4; ++j) {
          float xn = (y[j] - mean) * rstd * gg[c0 + j] + bb[c0 + j];
          QKV[r * QS + 128 + c0 + j] = xn;           // residual master for LN2
          sp1(Ahs, Als, r * AS + c0 + j, xn);        // A operand for ff1
        }
      }
    }
    __syncthreads();
    // ---- ff1: A[0..128) @ Wf1^T (N=256), hold in regs ----
    f32x4 dreg[MT][2];
    {
      const unsigned short* WH = Wf1H + (long)l * 256 * 128;
      const unsigned short* WL = Wf1L + (long)l * 256 * 128;
      #pragma unroll
      for (int ni = 0; ni < 2; ++ni) {
        int col = (wv + 8 * ni) * 16 + lr;
        const unsigned short* wp = WH + (long)col * 128 + (lq << 3);
        const unsigned short* wq = WL + (long)col * 128 + (lq << 3);
        f32x4 accH[MT], accL[MT];
        #pragma unroll
        for (int m = 0; m < MT; ++m) {
          accH[m] = (f32x4){0.f, 0.f, 0.f, 0.f};
          accL[m] = (f32x4){0.f, 0.f, 0.f, 0.f};
        }
        #pragma unroll
        for (int ks = 0; ks < 4; ++ks) {
          short8v bh = *(const short8v*)&wp[ks * 32];
          short8v bl = *(const short8v*)&wq[ks * 32];
          #pragma unroll
          for (int m = 0; m < MT; ++m) {
            int ao = (m * 16 + lr) * AS + (lq << 3) + ks * 32;
            short8v ah = *(const short8v*)&Ahs[ao];
            short8v al = *(const short8v*)&Als[ao];
            accL[m] = __builtin_amdgcn_mfma_f32_16x16x32_bf16(al, bh, accL[m], 0, 0, 0);
            accL[m] = __builtin_amdgcn_mfma_f32_16x16x32_bf16(ah, bl, accL[m], 0, 0, 0);
            accH[m] = __builtin_amdgcn_mfma_f32_16x16x32_bf16(ah, bh, accH[m], 0, 0, 0);
          }
        }
        #pragma unroll
        for (int m = 0; m < MT; ++m) {
          #pragma unroll
          for (int j = 0; j < 4; ++j) dreg[m][ni][j] = accH[m][j] + accL[m][j];
        }
      }
    }
    __syncthreads();   // all reads of A done
    // ---- ff1 write: relu + split -> A hi/lo [0..256) ----
    #pragma unroll
    for (int m = 0; m < MT; ++m) {
      #pragma unroll
      for (int ni = 0; ni < 2; ++ni) {
        int col = (wv + 8 * ni) * 16 + lr;
        float bv = Bf1[l * 256 + col];
        int r0 = m * 16 + (lq << 2);
        #pragma unroll
        for (int j = 0; j < 4; ++j) {
          float h = fmaxf(dreg[m][ni][j] + bv, 0.f);
          sp1(Ahs, Als, (r0 + j) * AS + col, h);
        }
      }
    }
    __syncthreads();
    // ---- ff2: A[0..256) @ Wf2^T (K=256) -> QKV fp32 [0..128) ----
    {
      const unsigned short* WH = Wf2H + (long)l * 128 * 256;
      const unsigned short* WL = Wf2L + (long)l * 128 * 256;
      int col = wv * 16 + lr;
      const unsigned short* wp = WH + (long)col * 256 + (lq << 3);
      const unsigned short* wq = WL + (long)col * 256 + (lq << 3);
      f32x4 accH[MT], accL[MT];
      #pragma unroll
      for (int m = 0; m < MT; ++m) {
        accH[m] = (f32x4){0.f, 0.f, 0.f, 0.f};
        accL[m] = (f32x4){0.f, 0.f, 0.f, 0.f};
      }
      #pragma unroll
      for (int ks = 0; ks < 8; ++ks) {
        short8v bh = *(const short8v*)&wp[ks * 32];
        short8v bl = *(const short8v*)&wq[ks * 32];
        #pragma unroll
        for (int m = 0; m < MT; ++m) {
          int ao = (m * 16 + lr) * AS + (lq << 3) + ks * 32;
          short8v ah = *(const short8v*)&Ahs[ao];
          short8v al = *(const short8v*)&Als[ao];
          accL[m] = __builtin_amdgcn_mfma_f32_16x16x32_bf16(al, bh, accL[m], 0, 0, 0);
          accL[m] = __builtin_amdgcn_mfma_f32_16x16x32_bf16(ah, bl, accL[m], 0, 0, 0);
          accH[m] = __builtin_amdgcn_mfma_f32_16x16x32_bf16(ah, bh, accH[m], 0, 0, 0);
        }
      }
      float bv = Bf2[l * 128 + col];
      #pragma unroll
      for (int m = 0; m < MT; ++m) {
        int r0 = m * 16 + (lq << 2);
        #pragma unroll
        for (int j = 0; j < 4; ++j)
          QKV[(r0 + j) * QS + col] = accH[m][j] + accL[m][j] + bv;
      }
    }
    __syncthreads();
    // ---- residual + LN2: y_resid(QKV[128..256)) + ff(QKV[0..128)) -> A hi/lo ----
    {
      const float* gg = Ln2g + l * cH;
      const float* bb = Ln2b + l * cH;
      #pragma unroll
      for (int p = 0; p < MT; ++p) {
        int r = p * 16 + (tid >> 5);
        int c0 = (tid & 31) * 4;
        float y[4]; float s = 0.f, s2 = 0.f;
        #pragma unroll
        for (int j = 0; j < 4; ++j) {
          float yv = QKV[r * QS + 128 + c0 + j] + QKV[r * QS + c0 + j];
          y[j] = yv; s += yv; s2 += yv * yv;
        }
        #pragma unroll
        for (int m = 1; m < 32; m <<= 1) { s += __shfl_xor(s, m, 32); s2 += __shfl_xor(s2, m, 32); }
        float mean = s * (1.f / 128.f);
        float rstd = rsqrtf(s2 * (1.f / 128.f) - mean * mean + 1e-5f);
        #pragma unroll
        for (int j = 0; j < 4; ++j) {
          float xn = (y[j] - mean) * rstd * gg[c0 + j] + bb[c0 + j];
          sp1(Ahs, Als, r * AS + c0 + j, xn);
        }
      }
    }
    __syncthreads();
  }

  // ---- H1 = mean over the 6 tokens ----
  for (int i = tid; i < ESETS * cH; i += 512) {
    int s = i >> 7, c = i & 127;
    float m = 0.f;
    #pragma unroll
    for (int t = 0; t < 6; ++t)
      m += b2f(Ahs[(s * 6 + t) * AS + c]) + b2f(Als[(s * 6 + t) * AS + c]);
    H1[(long)(base + s) * cH + c] = m * (1.f / 6.f);
  }
}

// ---------------- l2_batch = batch[ue0[l2nm0[i]]] ----------------
__global__ void l2b_k(const int* __restrict__ l2nm, const int* __restrict__ ue,
                      const int* __restrict__ batch, int* __restrict__ l2b) {
  int i = blockIdx.x * 256 + threadIdx.x;
  if (i < cL2) l2b[i] = batch[ue[l2nm[i]]];
}

// ---------------- pooling ----------------
__global__ void init_stats_k(float* sum, unsigned* mx, unsigned* mn, float* cnt) {
  int i = blockIdx.x * 256 + threadIdx.x;
  if (i < cG * cH) { sum[i] = 0.f; mx[i] = 0u; mn[i] = 0xFFFFFFFFu; }
  if (i < cG) cnt[i] = 0.f;
}

__global__ void pool_k(const float* __restrict__ X, const int* __restrict__ gidx,
                       float* sum, unsigned* mx, unsigned* mn, float* cnt,
                       int n, int do_relu) {
  long idx = (long)blockIdx.x * 256 + threadIdx.x;
  if (idx >= (long)n * 32) return;
  int i = (int)(idx >> 5), q = (int)(idx & 31) * 4;
  int g = gidx[i];
  float4 v = *(const float4*)&X[(long)i * cH + q];
  if (do_relu) {
    v.x = fmaxf(v.x, 0.f); v.y = fmaxf(v.y, 0.f);
    v.z = fmaxf(v.z, 0.f); v.w = fmaxf(v.w, 0.f);
  }
  long b = (long)g * cH + q;
  atomicAdd(&sum[b + 0], v.x); atomicAdd(&sum[b + 1], v.y);
  atomicAdd(&sum[b + 2], v.z); atomicAdd(&sum[b + 3], v.w);
  atomicMax(&mx[b + 0], fmap(v.x)); atomicMax(&mx[b + 1], fmap(v.y));
  atomicMax(&mx[b + 2], fmap(v.z)); atomicMax(&mx[b + 3], fmap(v.w));
  atomicMin(&mn[b + 0], fmap(v.x)); atomicMin(&mn[b + 1], fmap(v.y));
  atomicMin(&mn[b + 2], fmap(v.z)); atomicMin(&mn[b + 3], fmap(v.w));
  if (q == 0) atomicAdd(&cnt[g], 1.0f);
}

__global__ void pool_fin_k(const float* sum, const unsigned* mx, const unsigned* mn,
                           const float* cnt, float* Hp, int pool_idx) {
  int idx = blockIdx.x * 256 + threadIdx.x;
  if (idx >= cG * cH) return;
  int g = idx >> 7, c = idx & 127;
  float ct = cnt[g];
  float mean = sum[idx] / fmaxf(ct, 1.f);
  float mxv = (ct > 0.f) ? funmap(mx[idx]) : 0.f;
  float mnv = (ct > 0.f) ? funmap(mn[idx]) : 0.f;
  float* row = Hp + (long)g * (9 * cH) + pool_idx * 3 * cH;
  row[c] = mnv;
  row[cH + c] = mxv;
  row[2 * cH + c] = mean;
}

// ---------------- final MLP per graph ----------------
__global__ __launch_bounds__(128) void mlp_k(
    const float* __restrict__ Hp,
    const float* __restrict__ f0w, const float* __restrict__ f0b,
    const float* __restrict__ f0g, const float* __restrict__ f0bb,
    const float* __restrict__ f1w, const float* __restrict__ f1b,
    const float* __restrict__ f1g, const float* __restrict__ f1bb,
    const float* __restrict__ fow, const float* __restrict__ fob,
    float* __restrict__ out) {
  __shared__ float hin[1152];
  __shared__ float red[8];
  int g = blockIdx.x, tid = threadIdx.x;
  const float* hp = Hp + (long)g * 1152;
  for (int i = tid; i < 1152; i += 128) hin[i] = hp[i];
  __syncthreads();
  float acc = f0b[tid];
  {
    const float* wr = f0w + (long)tid * 1152;
    for (int k = 0; k < 1152; k += 4) {
      float4 w4 = *(const float4*)(wr + k);
      float4 h4 = *(const float4*)&hin[k];
      acc = fmaf(h4.x, w4.x, acc);
      acc = fmaf(h4.y, w4.y, acc);
      acc = fmaf(h4.z, w4.z, acc);
      acc = fmaf(h4.w, w4.w, acc);
    }
  }
  float s = acc, s2 = acc * acc;
  #pragma unroll
  for (int m = 1; m < 64; m <<= 1) { s += __shfl_xor(s, m); s2 += __shfl_xor(s2, m); }
  if ((tid & 63) == 0) { red[tid >> 6] = s; red[4 + (tid >> 6)] = s2; }
  __syncthreads();
  s = red[0] + red[1]; s2 = red[4] + red[5];
  {
    float mean = s * (1.f / 128.f);
    float rstd = rsqrtf(s2 * (1.f / 128.f) - mean * mean + 1e-5f);
    float xn = (acc - mean) * rstd * f0g[tid] + f0bb[tid];
    float h0 = gelu_exact(xn);
    __syncthreads();
    hin[tid] = h0;
  }
  __syncthreads();
  acc = f1b[tid];
  {
    const float* wr = f1w + (long)tid * 128;
    for (int k = 0; k < 128; k += 4) {
      float4 w4 = *(const float4*)(wr + k);
      float4 h4 = *(const float4*)&hin[k];
      acc = fmaf(h4.x, w4.x, acc);
      acc = fmaf(h4.y, w4.y, acc);
      acc = fmaf(h4.z, w4.z, acc);
      acc = fmaf(h4.w, w4.w, acc);
    }
  }
  s = acc; s2 = acc * acc;
  #pragma unroll
  for (int m = 1; m < 64; m <<= 1) { s += __shfl_xor(s, m); s2 += __shfl_xor(s2, m); }
  __syncthreads();
  if ((tid & 63) == 0) { red[tid >> 6] = s; red[4 + (tid >> 6)] = s2; }
  __syncthreads();
  s = red[0] + red[1]; s2 = red[4] + red[5];
  float h1;
  {
    float mean = s * (1.f / 128.f);
    float rstd = rsqrtf(s2 * (1.f / 128.f) - mean * mean + 1e-5f);
    float xn = (acc - mean) * rstd * f1g[tid] + f1bb[tid];
    h1 = gelu_exact(xn);
  }
  float p = h1 * fow[tid];
  #pragma unroll
  for (int m = 1; m < 64; m <<= 1) p += __shfl_xor(p, m);
  __syncthreads();
  if ((tid & 63) == 0) red[tid >> 6] = p;
  __syncthreads();
  if (tid == 0) out[g] = red[0] + red[1] + fob[0];
}

// ---------------- launcher ----------------
extern "C" void kernel_launch(void* const* d_in, const int* in_sizes, int n_in,
                              void* d_out, int out_size, void* d_ws, size_t ws_size,
                              hipStream_t stream) {
  const float* x     = (const float*)d_in[0];
  const float* ea    = (const float*)d_in[1];
  const int*   ei    = (const int*)d_in[2];
  const int*   ue    = (const int*)d_in[3];
  const int*   batch = (const int*)d_in[4];
  const int*   l2nm  = (const int*)d_in[5];
  const int*   l2ei  = (const int*)d_in[6];
  const float* lew   = (const float*)d_in[8];
  const float* leb   = (const float*)d_in[9];
  const float* g1w   = (const float*)d_in[10];
  const float* g1b   = (const float*)d_in[11];
  const float* g2w   = (const float*)d_in[12];
  const float* g2b   = (const float*)d_in[13];
  const float* tinw  = (const float*)d_in[14];
  const float* tinb  = (const float*)d_in[15];
  const float* toutw = (const float*)d_in[16];
  const float* toutb = (const float*)d_in[17];
  const float* tl1g  = (const float*)d_in[18];
  const float* tl1b  = (const float*)d_in[19];
  const float* tl2g  = (const float*)d_in[20];
  const float* tl2b  = (const float*)d_in[21];
  const float* tf1w  = (const float*)d_in[22];
  const float* tf1b  = (const float*)d_in[23];
  const float* tf2w  = (const float*)d_in[24];
  const float* tf2b  = (const float*)d_in[25];
  const float* f0w   = (const float*)d_in[26];
  const float* f0b   = (const float*)d_in[27];
  const float* f0g   = (const float*)d_in[28];
  const float* f0bb  = (const float*)d_in[29];
  const float* f1w   = (const float*)d_in[30];
  const float* f1b   = (const float*)d_in[31];
  const float* f1g   = (const float*)d_in[32];
  const float* f1bb  = (const float*)d_in[33];
  const float* fow   = (const float*)d_in[34];
  const float* fob   = (const float*)d_in[35];
  float* out = (float*)d_out;

  char* ws = (char*)d_ws;
  size_t off = 0;
  float* H1  = (float*)(ws + off);  off += (size_t)cL2 * cH * 4;
  float* RA  = (float*)(ws + off);  off += (size_t)cL2 * cH * 4;   // H0 then H2
  float* XW  = (float*)(ws + off);  off += (size_t)cL2 * cH * 4;
  float* DEG = (float*)(ws + off);  off += (size_t)cL2 * 4;
  int*   L2B = (int*)(ws + off);    off += (size_t)cL2 * 4;
  char*  ST  = ws + off;            off += 3 * ((size_t)cG * cH * 4 * 3 + cG * 4);
  float* Hp  = (float*)(ws + off);  off += (size_t)cG * 9 * cH * 4;
  // split-bf16 weight buffers
  unsigned short* WinH  = (unsigned short*)(ws + off); off += (size_t)cNL * 384 * 128 * 2;
  unsigned short* WinL  = (unsigned short*)(ws + off); off += (size_t)cNL * 384 * 128 * 2;
  unsigned short* WoutH = (unsigned short*)(ws + off); off += (size_t)cNL * 128 * 128 * 2;
  unsigned short* WoutL = (unsigned short*)(ws + off); off += (size_t)cNL * 128 * 128 * 2;
  unsigned short* Wf1H  = (unsigned short*)(ws + off); off += (size_t)cNL * 256 * 128 * 2;
  unsigned short* Wf1L  = (unsigned short*)(ws + off); off += (size_t)cNL * 256 * 128 * 2;
  unsigned short* Wf2H  = (unsigned short*)(ws + off); off += (size_t)cNL * 128 * 256 * 2;
  unsigned short* Wf2L  = (unsigned short*)(ws + off); off += (size_t)cNL * 128 * 256 * 2;
  float* H0 = RA;
  float* H2 = RA;

  auto stat = [&](int p) {
    size_t stride = (size_t)cG * cH * 4 * 3 + cG * 4;
    char* b = ST + p * stride;
    struct S { float* sum; unsigned* mx; unsigned* mn; float* cnt; } s;
    s.sum = (float*)b;
    s.mx  = (unsigned*)(b + (size_t)cG * cH * 4);
    s.mn  = (unsigned*)(b + (size_t)cG * cH * 8);
    s.cnt = (float*)(b + (size_t)cG * cH * 12);
    return s;
  };
  auto s0 = stat(0), s1 = stat(1), s2 = stat(2);

  // 0) split transformer weights into bf16 hi/lo
  split_w_k<<<(cNL * 384 * 128 + 255) / 256, 256, 0, stream>>>(tinw, WinH, WinL, cNL * 384 * 128);
  split_w_k<<<(cNL * 128 * 128 + 255) / 256, 256, 0, stream>>>(toutw, WoutH, WoutL, cNL * 128 * 128);
  split_w_k<<<(cNL * 256 * 128 + 255) / 256, 256, 0, stream>>>(tf1w, Wf1H, Wf1L, cNL * 256 * 128);
  split_w_k<<<(cNL * 128 * 256 + 255) / 256, 256, 0, stream>>>(tf2w, Wf2H, Wf2L, cNL * 128 * 256);

  // 1) GCN1 -> H0
  gemm128_k<<<(cN + 127) / 128, 256, 0, stream>>>(x, g1w, XW, cN);
  fill_k<<<(cN + 255) / 256, 256, 0, stream>>>(DEG, 1.0f, cN);
  deg_count_k<<<(cE + 255) / 256, 256, 0, stream>>>(ei, DEG, cE);
  to_dinv_k<<<(cN + 255) / 256, 256, 0, stream>>>(DEG, cN);
  gcn_init_k<<<(cN * 32 + 255) / 256, 256, 0, stream>>>(XW, DEG, g1b, H0, cN);
  gcn_agg_k<<<(int)(((long)cE * 32 + 255) / 256), 256, 0, stream>>>(XW, DEG, ei, H0, cE);

  // 2) fused MFMA transformer encoder -> H1
  hipFuncSetAttribute(reinterpret_cast<const void*>(encoder_k),
                      hipFuncAttributeMaxDynamicSharedMemorySize, 131072);
  encoder_k<<<cL2 / ESETS, 512, SMEM_SZ, stream>>>(H0, ea, lew, leb, ue, l2nm,
      WinH, WinL, tinb, WoutH, WoutL, toutb, tl1g, tl1b, tl2g, tl2b,
      Wf1H, Wf1L, tf1b, Wf2H, Wf2L, tf2b, H1);

  // 3) l2_batch
  l2b_k<<<(cL2 + 255) / 256, 256, 0, stream>>>(l2nm, ue, batch, L2B);
  // 4) pool H0 now (frees RA for H2)
  init_stats_k<<<(cG * cH + 255) / 256, 256, 0, stream>>>(s0.sum, s0.mx, s0.mn, s0.cnt);
  pool_k<<<(int)(((long)cN * 32 + 255) / 256), 256, 0, stream>>>(H0, batch, s0.sum, s0.mx, s0.mn, s0.cnt, cN, 0);
  pool_fin_k<<<(cG * cH + 255) / 256, 256, 0, stream>>>(s0.sum, s0.mx, s0.mn, s0.cnt, Hp, 0);
  // 5) GCN2 -> H2
  gemm128_k<<<(cL2 + 127) / 128, 256, 0, stream>>>(H1, g2w, XW, cL2);
  fill_k<<<(cL2 + 255) / 256, 256, 0, stream>>>(DEG, 1.0f, cL2);
  deg_count_k<<<(cEL + 255) / 256, 256, 0, stream>>>(l2ei, DEG, cEL);
  to_dinv_k<<<(cL2 + 255) / 256, 256, 0, stream>>>(DEG, cL2);
  gcn_init_k<<<(cL2 * 32 + 255) / 256, 256, 0, stream>>>(XW, DEG, g2b, H2, cL2);
  gcn_agg_k<<<(int)(((long)cEL * 32 + 255) / 256), 256, 0, stream>>>(XW, DEG, l2ei, H2, cEL);
  // 6) pool H1 and H2
  init_stats_k<<<(cG * cH + 255) / 256, 256, 0, stream>>>(s1.sum, s1.mx, s1.mn, s1.cnt);
  init_stats_k<<<(cG * cH + 255) / 256, 256, 0, stream>>>(s2.sum, s2.mx, s2.mn, s2.cnt);
  pool_k<<<(int)(((long)cL2 * 32 + 255) / 256), 256, 0, stream>>>(H1, L2B, s1.sum, s1.mx, s1.mn, s1.cnt, cL2, 0);
  pool_k<<<(int)(((long)cL2 * 32 + 255) / 256), 256, 0, stream>>>(H2, L2B, s2.sum, s2.mx, s2.mn, s2.cnt, cL2, 1);
  pool_fin_k<<<(cG * cH + 255) / 256, 256, 0, stream>>>(s1.sum, s1.mx, s1.mn, s1.cnt, Hp, 1);
  pool_fin_k<<<(cG * cH + 255) / 256, 256, 0, stream>>>(s2.sum, s2.mx, s2.mn, s2.cnt, Hp, 2);
  // 7) final MLP -> out[512]
  mlp_k<<<cG, 128, 0, stream>>>(Hp, f0w, f0b, f0g, f0bb, f1w, f1b, f1g, f1bb, fow, fob, out);
}